// Round 4
// baseline (219.469 us; speedup 1.0000x reference)
//
#include <hip/hip_runtime.h>
#include <hip/hip_bf16.h>

using bf16 = __hip_bfloat16;
typedef __attribute__((ext_vector_type(4))) float f32x4;
typedef __attribute__((ext_vector_type(8))) short short8;

#define SEQ 4096
#define DIM 768

// r13 (resubmit after infra failure; never measured): conflict-free
// "fragment-order" LDS layout in BOTH gemm cores.
//   Stage lane-map changed to (row = lane&15, chunk = lane>>4) so that
//   global_load_lds's linear lane-order write places each 16x32 subtile in
//   LDS in exactly the order MFMA fragment reads consume it. Every
//   ds_read_b128 is then uniform_base + lane*16B -> zero bank conflicts by
//   construction (r12 measured SQ_LDS_BANK_CONFLICT=2.36M/dispatch on score;
//   8-way row aliasing in the 64B-row layout). Global coalescing unchanged
//   (same 64B row segments, address-based coalescer). Score pipeline
//   structure (depth-4 queue, counted vmcnt, setprio) unchanged to isolate
//   the T2 effect. r12: 173.1us (score 48.8); predicted ~145us.

// ---- fused fp32 -> bf16 canonicalization (RNE) + denom zeroing ----
__global__ void convert_all_kernel(const float* __restrict__ x,
                                   const float* __restrict__ wq,
                                   const float* __restrict__ wk,
                                   const float* __restrict__ wv,
                                   bf16* __restrict__ xc, bf16* __restrict__ wqc,
                                   bf16* __restrict__ wkc, bf16* __restrict__ wvc,
                                   float* __restrict__ denom) {
  const int XB = (SEQ * DIM) / 2048;   // 1536
  const int WB = (DIM * DIM) / 2048;   // 288
  int b = blockIdx.x;
  if (b == 0) {  // zero denom[4096]
    float4 z = {0.f, 0.f, 0.f, 0.f};
#pragma unroll
    for (int q = 0; q < 4; q++)
      *(float4*)(denom + threadIdx.x * 4 + q * 1024) = z;
  }
  const float* src; bf16* dst; int off;
  if (b < XB)               { src = x;  dst = xc;  off = b * 2048; }
  else if (b < XB + WB)     { src = wq; dst = wqc; off = (b - XB) * 2048; }
  else if (b < XB + 2 * WB) { src = wk; dst = wkc; off = (b - XB - WB) * 2048; }
  else                      { src = wv; dst = wvc; off = (b - XB - 2 * WB) * 2048; }
  int i = off + threadIdx.x * 8;
  float4 f0 = *(const float4*)(src + i);
  float4 f1 = *(const float4*)(src + i + 4);
  bf16 tmp[8];
  tmp[0] = __float2bfloat16(f0.x); tmp[1] = __float2bfloat16(f0.y);
  tmp[2] = __float2bfloat16(f0.z); tmp[3] = __float2bfloat16(f0.w);
  tmp[4] = __float2bfloat16(f1.x); tmp[5] = __float2bfloat16(f1.y);
  tmp[6] = __float2bfloat16(f1.z); tmp[7] = __float2bfloat16(f1.w);
  *(uint4*)(dst + i) = *(const uint4*)tmp;
}

// ============ shared helpers ============
__device__ __forceinline__ void gload_lds16(const bf16* g, bf16* l) {
  __builtin_amdgcn_global_load_lds(
      (const __attribute__((address_space(1))) void*)g,
      (__attribute__((address_space(3))) void*)l,
      16, 0, 0);
}

// ============ BT-GEMM core (m97-class, qkv/pv) ============
// Fragment-order staging: lane l loads global (row = l&15, chunk = l>>4) of a
// 16x32 subtile; global_load_lds writes lane-linear, so LDS slot l holds
// exactly what fragment-lane l reads. Reads become uniform+lane*16B.
__device__ __forceinline__ void stage64(const bf16* g, int ldk, bf16* l,
                                        int wave, int lane) {
  int r = lane & 15;            // row within 16-row subtile
  int c = (lane >> 4) * 8;      // elem chunk 0,8,16,24
  const bf16* gw = g + (size_t)(wave * 32) * ldk;
  bf16* lw = l + wave * 1024;
#pragma unroll
  for (int h = 0; h < 2; h++)
#pragma unroll
    for (int s = 0; s < 2; s++)
      gload_lds16(gw + (size_t)(s * 16 + r) * ldk + h * 32 + c,
                  lw + h * 4096 + s * 512);
}

__device__ __forceinline__ void gemm_core(const bf16* __restrict__ A,
                                          const bf16* __restrict__ B,
                                          int ldk, int klen, int m0, int n0,
                                          f32x4 acc[4][4],
                                          bf16* lA, bf16* lB) {
  const int tid  = threadIdx.x;
  const int wave = tid >> 6, lane = tid & 63;
  const int wm = (wave & 1) * 64, wn = (wave >> 1) * 64;
  const bf16* Abase = A + (size_t)m0 * ldk;
  const bf16* Bbase = B + (size_t)n0 * ldk;
  const int sma = (wm >> 4);   // A subtile base index (0 or 4)
  const int smb = (wn >> 4);   // B subtile base index
  for (int kk = 0; kk < klen; kk += 64) {
    stage64(Abase + kk, ldk, lA, wave, lane);
    stage64(Bbase + kk, ldk, lB, wave, lane);
    __syncthreads();  // vmcnt drain (DMA done) + barrier
#pragma unroll
    for (int h = 0; h < 2; h++) {
      short8 af[4], bfr[4];
#pragma unroll
      for (int i = 0; i < 4; i++)
        af[i] = *(const short8*)&lA[h * 4096 + (sma + i) * 512 + lane * 8];
#pragma unroll
      for (int j = 0; j < 4; j++)
        bfr[j] = *(const short8*)&lB[h * 4096 + (smb + j) * 512 + lane * 8];
#pragma unroll
      for (int i = 0; i < 4; i++)
#pragma unroll
        for (int j = 0; j < 4; j++)
          acc[i][j] = __builtin_amdgcn_mfma_f32_16x16x32_bf16(af[i], bfr[j], acc[i][j], 0, 0, 0);
    }
    __syncthreads();
  }
}

// C/D layout (verified m89/m91): col = lane&15, row = (lane>>4)*4 + reg.

// ---- K1: fused QKV projection. grid (32, 18), XCD-swizzled. Q gets softmax
// scale folded; V written transposed via LDS transpose.
__global__ __launch_bounds__(256, 3) void qkv_kernel(
    const bf16* __restrict__ x, const bf16* __restrict__ Wq,
    const bf16* __restrict__ Wk, const bf16* __restrict__ Wv,
    bf16* __restrict__ Q, bf16* __restrict__ Kb, bf16* __restrict__ Vt) {
  __shared__ __align__(16) bf16 smem[16384];  // lA|lB for gemm; tile for transpose
  bf16* lA = smem;
  bf16* lB = smem + 8192;
  // swizzle: XCD (id%8) gets m-slab of 4 tiles x all 18 n-tiles (x-slab hot in L2)
  const int id  = blockIdx.y * 32 + blockIdx.x;  // 0..575
  const int xcd = id & 7;
  const int k   = id >> 3;                       // 0..71
  const int m0  = (xcd * 4 + (k & 3)) * 128;
  const int n0g = (k >> 2) * 128;                // 0..17 tiles
  const int wsel = n0g / DIM;          // 0=Q 1=K 2=V (uniform per block)
  const int n0   = n0g % DIM;
  const bf16* W = (wsel == 0) ? Wq : (wsel == 1) ? Wk : Wv;
  f32x4 acc[4][4] = {};
  gemm_core(x, W, DIM, DIM, m0, n0, acc, lA, lB);

  const int tid = threadIdx.x, wave = tid >> 6, lane = tid & 63;
  const int wm = (wave & 1) * 64, wn = (wave >> 1) * 64;
  const int g = lane >> 4, lr = lane & 15;
  const float scale = 0.03608439182435161f;  // 1/sqrt(768)

  if (wsel == 2) {
    // Two-phase 128x64 LDS transpose; stride 67 spreads banks.
    bf16* tile = smem;
#pragma unroll
    for (int ph = 0; ph < 2; ph++) {
      __syncthreads();
      if ((wave >> 1) == ph) {
#pragma unroll
        for (int i = 0; i < 4; i++)
#pragma unroll
          for (int j = 0; j < 4; j++)
#pragma unroll
            for (int r = 0; r < 4; r++)
              tile[(wm + i * 16 + g * 4 + r) * 67 + j * 16 + lr] =
                  __float2bfloat16(acc[i][j][r]);
      }
      __syncthreads();
      int cl = tid >> 2;          // column within this 64-col half
      int r0 = (tid & 3) * 32;    // row segment
      bf16 vals[32];
#pragma unroll
      for (int q = 0; q < 32; q++) vals[q] = tile[(r0 + q) * 67 + cl];
      bf16* dst = Vt + (size_t)(n0 + ph * 64 + cl) * SEQ + m0 + r0;
#pragma unroll
      for (int q = 0; q < 4; q++)
        *(uint4*)(dst + q * 8) = *(const uint4*)(vals + q * 8);
    }
  } else {
    bf16* dstm = (wsel == 0) ? Q : Kb;
    float fs = (wsel == 0) ? scale : 1.0f;
#pragma unroll
    for (int i = 0; i < 4; i++)
#pragma unroll
      for (int j = 0; j < 4; j++)
#pragma unroll
        for (int r = 0; r < 4; r++) {
          int row = m0 + wm + i * 16 + g * 4 + r;
          int col = n0 + wn + j * 16 + lr;
          dstm[row * DIM + col] = __float2bfloat16(acc[i][j][r] * fs);
        }
  }
}

// ---- K2: S = Q K^T; P = exp(S); row sums -> denom.
// 256x256-tile deep-pipelined core: 512 thr, 8 waves (2Mx4N), BK=32,
// 4-deep LDS K-tile queue, counted vmcnt(8), setprio around MFMA.
// r13: fragment-order staging -> all ds_read_b128 are lane-linear,
// zero bank conflicts. grid (16,16) = 256 blocks = 1/CU; XCD-swizzled.
#define SC_NT (DIM / 32)   // 24 K-tiles

__global__ __launch_bounds__(512, 2) void score_kernel(
    const bf16* __restrict__ Q, const bf16* __restrict__ Kb,
    bf16* __restrict__ P, float* __restrict__ denom) {
  // A queue: 4 x [16 subtiles x 512] at smem+0 ; B queue at smem+32768
  __shared__ __align__(16) bf16 smem[65536];   // 128 KiB
  const int tid  = threadIdx.x;
  const int wave = tid >> 6, lane = tid & 63;
  const int g = lane >> 4, lr = lane & 15;
  const int wm = wave >> 2, wn = wave & 3;     // 2M x 4N wave grid

  const int id  = blockIdx.y * 16 + blockIdx.x;  // 0..255
  const int xcd = id & 7;
  const int k   = id >> 3;                       // 0..31
  const int m0  = (xcd * 2 + (k & 1)) * 256;     // 16 m-tiles
  const int n0  = (k >> 1) * 256;                // 16 n-tiles

  const bf16* Abase = Q  + (size_t)m0 * DIM;
  const bf16* Bbase = Kb + (size_t)n0 * DIM;

  // fragment-order stage: lane loads (row = lane&15, chunk = lane>>4) so the
  // lane-linear LDS write leaves the subtile in fragment-read order.
  const int srow = lane & 15;
  const int scol = (lane >> 4) * 8;

  // STAGE(TT,H): 16-row subtile at rows H*128 + wave*16 of K-tile TT, A and B.
#define SC_STAGE(TT, H)                                                        \
  {                                                                            \
    const int rb = (H) * 128 + wave * 16;                                      \
    const size_t go = (size_t)(rb + srow) * DIM + (TT) * 32 + scol;            \
    bf16* sa = smem + ((TT) & 3) * 8192 + rb * 32;                             \
    bf16* sb = smem + 32768 + ((TT) & 3) * 8192 + rb * 32;                     \
    gload_lds16(Abase + go, sa);                                               \
    gload_lds16(Bbase + go, sb);                                               \
  }

  f32x4 acc[8][4] = {};   // 8 m-frags x 4 n-frags

  // prologue: stage K-tiles 0,1,2 (12 loads/lane); tile0 landed after vmcnt(8)
#pragma unroll
  for (int t = 0; t < 3; ++t) {
    SC_STAGE(t, 0);
    SC_STAGE(t, 1);
  }
  asm volatile("s_waitcnt vmcnt(8)" ::: "memory");
  __builtin_amdgcn_s_barrier();

  short8 bfr[4], af[4];
  for (int T = 0; T < SC_NT; ++T) {
    bf16* sA = smem + (T & 3) * 8192;
    bf16* sB = smem + 32768 + (T & 3) * 8192;
    // ---------- phase 0: B all 4 n-frags + A m-frags 0..3 ----------
#pragma unroll
    for (int j = 0; j < 4; ++j)
      bfr[j] = *(const short8*)&sB[(wn * 4 + j) * 512 + lane * 8];
#pragma unroll
    for (int i = 0; i < 4; ++i)
      af[i] = *(const short8*)&sA[(wm * 8 + i) * 512 + lane * 8];
    if (T + 3 < SC_NT) SC_STAGE(T + 3, 0);
    __builtin_amdgcn_s_barrier();
    asm volatile("s_waitcnt lgkmcnt(0)" ::: "memory");
    __builtin_amdgcn_sched_barrier(0);
    __builtin_amdgcn_s_setprio(1);
#pragma unroll
    for (int i = 0; i < 4; ++i)
#pragma unroll
      for (int j = 0; j < 4; ++j)
        acc[i][j] = __builtin_amdgcn_mfma_f32_16x16x32_bf16(af[i], bfr[j], acc[i][j], 0, 0, 0);
    __builtin_amdgcn_s_setprio(0);
    __builtin_amdgcn_s_barrier();
    // ---------- phase 1: A m-frags 4..7 (B reused from regs) ----------
#pragma unroll
    for (int i = 0; i < 4; ++i)
      af[i] = *(const short8*)&sA[(wm * 8 + 4 + i) * 512 + lane * 8];
    if (T + 3 < SC_NT) {
      SC_STAGE(T + 3, 1);
      asm volatile("s_waitcnt vmcnt(8)" ::: "memory");  // tile T+1 landed
    } else {
      asm volatile("s_waitcnt vmcnt(0)" ::: "memory");  // tail drain
    }
    __builtin_amdgcn_s_barrier();
    asm volatile("s_waitcnt lgkmcnt(0)" ::: "memory");
    __builtin_amdgcn_sched_barrier(0);
    __builtin_amdgcn_s_setprio(1);
#pragma unroll
    for (int i = 0; i < 4; ++i)
#pragma unroll
      for (int j = 0; j < 4; ++j)
        acc[4 + i][j] = __builtin_amdgcn_mfma_f32_16x16x32_bf16(af[i], bfr[j], acc[4 + i][j], 0, 0, 0);
    __builtin_amdgcn_s_setprio(0);
    __builtin_amdgcn_s_barrier();
  }
#undef SC_STAGE

  // epilogue: exp, P write, denom atomics. C/D: col=lr, row=g*4+reg.
  const int mrow = m0 + wm * 128;
  const int ncol = n0 + wn * 64;
#pragma unroll
  for (int i = 0; i < 8; ++i) {
    float rsum[4] = {0.f, 0.f, 0.f, 0.f};
#pragma unroll
    for (int j = 0; j < 4; ++j)
#pragma unroll
      for (int r = 0; r < 4; ++r) {
        float p = __expf(acc[i][j][r]);
        int row = mrow + i * 16 + g * 4 + r;
        int col = ncol + j * 16 + lr;
        P[(size_t)row * SEQ + col] = __float2bfloat16(p);
        rsum[r] += p;
      }
#pragma unroll
    for (int r = 0; r < 4; ++r) {
      float s = rsum[r];
      s += __shfl_xor(s, 1);
      s += __shfl_xor(s, 2);
      s += __shfl_xor(s, 4);
      s += __shfl_xor(s, 8);
      if (lr == 0) atomicAdd(&denom[mrow + i * 16 + g * 4 + r], s);
    }
  }
}

// ---- K3a: split-K PV. grid (32, 6, 4), XCD-swizzled. bf16 partials.
__global__ __launch_bounds__(256, 3) void pv_kernel(
    const bf16* __restrict__ P, const bf16* __restrict__ Vt,
    bf16* __restrict__ partial) {
  __shared__ __align__(16) bf16 smem[16384];
  bf16* lA = smem;
  bf16* lB = smem + 8192;
  // swizzle: XCD gets 3 (z,n) pairs x all 32 m: Vt chunk (256KB) L2-hot
  // across the 32 consecutive same-XCD blocks that reuse it.
  const int id  = (blockIdx.z * 6 + blockIdx.y) * 32 + blockIdx.x;  // 0..767
  const int xcd = id & 7;
  const int k   = id >> 3;          // 0..95
  const int m0  = (k & 31) * 128;
  const int pairid = xcd * 3 + (k >> 5);  // 0..23
  const int zz  = pairid / 6;
  const int n0  = (pairid % 6) * 128;
  const int kbase = zz * (SEQ / 4);
  f32x4 acc[4][4] = {};
  gemm_core(P + kbase, Vt + kbase, SEQ, SEQ / 4, m0, n0, acc, lA, lB);

  bf16* pout = partial + (size_t)zz * SEQ * DIM;
  const int tid = threadIdx.x, wave = tid >> 6, lane = tid & 63;
  const int wm = (wave & 1) * 64, wn = (wave >> 1) * 64;
  const int g = lane >> 4, lr = lane & 15;
#pragma unroll
  for (int i = 0; i < 4; i++)
#pragma unroll
    for (int j = 0; j < 4; j++)
#pragma unroll
      for (int r = 0; r < 4; r++) {
        int row = m0 + wm + i * 16 + g * 4 + r;
        int col = n0 + wn + j * 16 + lr;
        pout[row * DIM + col] = __float2bfloat16(acc[i][j][r]);
      }
}

// ---- K3b: out = (sum_z partial[z]) / denom[row]. 8 elems/thread.
__global__ __launch_bounds__(256) void reduce_kernel(
    const bf16* __restrict__ partial, const float* __restrict__ denom,
    float* __restrict__ out) {
  const size_t stride = (size_t)SEQ * DIM;
  int i = (blockIdx.x * 256 + threadIdx.x) * 8;
  uint4 u0 = *(const uint4*)(partial + i);
  uint4 u1 = *(const uint4*)(partial + stride + i);
  uint4 u2 = *(const uint4*)(partial + 2 * stride + i);
  uint4 u3 = *(const uint4*)(partial + 3 * stride + i);
  bf16 a0[8], a1[8], a2[8], a3[8];
  *(uint4*)a0 = u0; *(uint4*)a1 = u1; *(uint4*)a2 = u2; *(uint4*)a3 = u3;
  float inv = 1.0f / denom[i / DIM];   // 8 | DIM: all 8 elems same row
  float o[8];
#pragma unroll
  for (int k = 0; k < 8; k++)
    o[k] = (__bfloat162float(a0[k]) + __bfloat162float(a1[k]) +
            __bfloat162float(a2[k]) + __bfloat162float(a3[k])) * inv;
  *(float4*)(out + i)     = *(const float4*)(o);
  *(float4*)(out + i + 4) = *(const float4*)(o + 4);
}

extern "C" void kernel_launch(void* const* d_in, const int* in_sizes, int n_in,
                              void* d_out, int out_size, void* d_ws, size_t ws_size,
                              hipStream_t stream) {
  const float* x_raw  = (const float*)d_in[0];
  const float* Wq_raw = (const float*)d_in[1];
  const float* Wk_raw = (const float*)d_in[2];
  const float* Wv_raw = (const float*)d_in[3];
  float* out = (float*)d_out;

  // ws layout (~86 MB):
  //   xc bf16 [4096][768], Wqc/Wkc/Wvc bf16 [768][768]
  //   Q bf16 [4096][768] (pre-scaled), Kb bf16 [4096][768], Vt bf16 [768][4096]
  //   P bf16 [4096][4096], denom f32 [4096], partial bf16 [4][4096][768]
  bf16* xc  = (bf16*)d_ws;
  bf16* Wqc = xc  + (size_t)SEQ * DIM;
  bf16* Wkc = Wqc + (size_t)DIM * DIM;
  bf16* Wvc = Wkc + (size_t)DIM * DIM;
  bf16* Q   = Wvc + (size_t)DIM * DIM;
  bf16* Kb  = Q   + (size_t)SEQ * DIM;
  bf16* Vt  = Kb  + (size_t)SEQ * DIM;
  bf16* P   = Vt  + (size_t)DIM * SEQ;
  float* denom  = (float*)(P + (size_t)SEQ * SEQ);
  bf16* partial = (bf16*)(denom + SEQ);

  const int nx = SEQ * DIM;   // 3,145,728
  const int nw = DIM * DIM;   //   589,824
  const int conv_blocks = nx / 2048 + 3 * (nw / 2048);  // 2400

  convert_all_kernel<<<conv_blocks, 256, 0, stream>>>(
      x_raw, Wq_raw, Wk_raw, Wv_raw, xc, Wqc, Wkc, Wvc, denom);
  qkv_kernel<<<dim3(SEQ / 128, 2304 / 128), 256, 0, stream>>>(xc, Wqc, Wkc, Wvc, Q, Kb, Vt);
  score_kernel<<<dim3(16, 16), 512, 0, stream>>>(Q, Kb, P, denom);
  pv_kernel<<<dim3(SEQ / 128, DIM / 128, 4), 256, 0, stream>>>(P, Vt, partial);
  reduce_kernel<<<nx / 8 / 256, 256, 0, stream>>>(partial, denom, out);
}

// Round 5
// 175.355 us; speedup vs baseline: 1.2516x; 1.2516x over previous
//
#include <hip/hip_runtime.h>
#include <hip/hip_bf16.h>

using bf16 = __hip_bfloat16;
typedef __attribute__((ext_vector_type(4))) float f32x4;
typedef __attribute__((ext_vector_type(8))) short short8;

#define SEQ 4096
#define DIM 768

// r14: fragment-TILED GLOBAL layout for all GEMM operands (xc, W*, Q, Kb,
// Vt, P). Each [R][K] matrix is stored as 16x32 blocks (1024B); within a
// block, slot s = ((k%32)/8)*16 + r%16 holds 8 k-elems -> exactly the MFMA
// fragment order. Staging is then base + lane*16B: ONE contiguous 1KB wave
// read (fixes r13's global-coalescing break: lanes 0-15 hit 16 rows 1536B
// apart -> ~4x VMEM transactions, pv 57.6us/MfmaUtil 16%) AND lane-linear
// LDS (keeps r13's SQ_LDS_BANK_CONFLICT = 0, verified). Producers write
// address-permuted (convert/Vt stay 16B-vectorized; epilogues scalar as
// before). partial/out stay row-major. r12 173us, r13 219us; pred ~135us.

__device__ __forceinline__ size_t tiled_off(int r, int c, int K) {
  // bf16-element offset of (r,c) in a fragment-tiled [R][K] matrix
  return (size_t)(r >> 4) * 16 * K + ((size_t)(c >> 5) << 9) +
         (size_t)((((c >> 3) & 3) << 4) + (r & 15)) * 8 + (c & 7);
}

// ---- fused fp32 -> bf16 canonicalization (RNE) + denom zeroing ----
// writes bf16 in fragment-tiled layout (16B chunks -> one slot each)
__global__ void convert_all_kernel(const float* __restrict__ x,
                                   const float* __restrict__ wq,
                                   const float* __restrict__ wk,
                                   const float* __restrict__ wv,
                                   bf16* __restrict__ xc, bf16* __restrict__ wqc,
                                   bf16* __restrict__ wkc, bf16* __restrict__ wvc,
                                   float* __restrict__ denom) {
  const int XB = (SEQ * DIM) / 2048;   // 1536
  const int WB = (DIM * DIM) / 2048;   // 288
  int b = blockIdx.x;
  if (b == 0) {  // zero denom[4096]
    float4 z = {0.f, 0.f, 0.f, 0.f};
#pragma unroll
    for (int q = 0; q < 4; q++)
      *(float4*)(denom + threadIdx.x * 4 + q * 1024) = z;
  }
  const float* src; bf16* dst; int off;
  if (b < XB)               { src = x;  dst = xc;  off = b * 2048; }
  else if (b < XB + WB)     { src = wq; dst = wqc; off = (b - XB) * 2048; }
  else if (b < XB + 2 * WB) { src = wk; dst = wkc; off = (b - XB - WB) * 2048; }
  else                      { src = wv; dst = wvc; off = (b - XB - 2 * WB) * 2048; }
  int i = off + threadIdx.x * 8;       // flat index; 8 | i
  float4 f0 = *(const float4*)(src + i);
  float4 f1 = *(const float4*)(src + i + 4);
  bf16 tmp[8];
  tmp[0] = __float2bfloat16(f0.x); tmp[1] = __float2bfloat16(f0.y);
  tmp[2] = __float2bfloat16(f0.z); tmp[3] = __float2bfloat16(f0.w);
  tmp[4] = __float2bfloat16(f1.x); tmp[5] = __float2bfloat16(f1.y);
  tmp[6] = __float2bfloat16(f1.z); tmp[7] = __float2bfloat16(f1.w);
  int r = i / DIM, c = i % DIM;        // c multiple of 8
  *(uint4*)(dst + tiled_off(r, c, DIM)) = *(const uint4*)tmp;
}

// ============ shared helpers ============
__device__ __forceinline__ void gload_lds16(const bf16* g, bf16* l) {
  __builtin_amdgcn_global_load_lds(
      (const __attribute__((address_space(1))) void*)g,
      (__attribute__((address_space(3))) void*)l,
      16, 0, 0);
}

// ============ BT-GEMM core on tiled operands (m97-class, qkv/pv) ============
// Stage: one instruction = one 16x32 block = contiguous 1KB (lane*16B),
// lands in LDS already in fragment-read order. Reads lane-linear (0-conflict).
__device__ __forceinline__ void gemm_core_t(const bf16* __restrict__ At,
                                            const bf16* __restrict__ Bt,
                                            int Kblk /* K/32 */, int nkt,
                                            int m0, int n0, int kt0,
                                            f32x4 acc[4][4],
                                            bf16* lA, bf16* lB) {
  const int tid  = threadIdx.x;
  const int wave = tid >> 6, lane = tid & 63;
  const int sma = (wave & 1) * 4;   // A subtile base (0 or 4)
  const int smb = (wave >> 1) * 4;  // B subtile base
  const int rtA = m0 >> 4, rtB = n0 >> 4;
  for (int t = 0; t < nkt; t += 2) {
    const int ktb = kt0 + t;
#pragma unroll
    for (int h = 0; h < 2; h++)
#pragma unroll
      for (int s = 0; s < 2; s++) {
        gload_lds16(At + ((size_t)(rtA + wave * 2 + s) * Kblk + ktb + h) * 512 + lane * 8,
                    lA + wave * 1024 + h * 4096 + s * 512);
        gload_lds16(Bt + ((size_t)(rtB + wave * 2 + s) * Kblk + ktb + h) * 512 + lane * 8,
                    lB + wave * 1024 + h * 4096 + s * 512);
      }
    __syncthreads();  // vmcnt drain (DMA done) + barrier
#pragma unroll
    for (int h = 0; h < 2; h++) {
      short8 af[4], bfr[4];
#pragma unroll
      for (int i = 0; i < 4; i++)
        af[i] = *(const short8*)&lA[h * 4096 + (sma + i) * 512 + lane * 8];
#pragma unroll
      for (int j = 0; j < 4; j++)
        bfr[j] = *(const short8*)&lB[h * 4096 + (smb + j) * 512 + lane * 8];
#pragma unroll
      for (int i = 0; i < 4; i++)
#pragma unroll
        for (int j = 0; j < 4; j++)
          acc[i][j] = __builtin_amdgcn_mfma_f32_16x16x32_bf16(af[i], bfr[j], acc[i][j], 0, 0, 0);
    }
    __syncthreads();
  }
}

// C/D layout (verified m89/m91): col = lane&15, row = (lane>>4)*4 + reg.

// ---- K1: fused QKV projection. grid (32, 18), XCD-swizzled. Q gets softmax
// scale folded; Q/Kb written fragment-tiled; V written transposed+tiled.
__global__ __launch_bounds__(256, 3) void qkv_kernel(
    const bf16* __restrict__ x, const bf16* __restrict__ Wq,
    const bf16* __restrict__ Wk, const bf16* __restrict__ Wv,
    bf16* __restrict__ Q, bf16* __restrict__ Kb, bf16* __restrict__ Vt) {
  __shared__ __align__(16) bf16 smem[16384];  // lA|lB for gemm; tile for transpose
  bf16* lA = smem;
  bf16* lB = smem + 8192;
  // swizzle: XCD (id%8) gets m-slab of 4 tiles x all 18 n-tiles (x-slab hot in L2)
  const int id  = blockIdx.y * 32 + blockIdx.x;  // 0..575
  const int xcd = id & 7;
  const int k   = id >> 3;                       // 0..71
  const int m0  = (xcd * 4 + (k & 3)) * 128;
  const int n0g = (k >> 2) * 128;                // 0..17 tiles
  const int wsel = n0g / DIM;          // 0=Q 1=K 2=V (uniform per block)
  const int n0   = n0g % DIM;
  const bf16* W = (wsel == 0) ? Wq : (wsel == 1) ? Wk : Wv;
  f32x4 acc[4][4] = {};
  gemm_core_t(x, W, DIM / 32, DIM / 32, m0, n0, 0, acc, lA, lB);

  const int tid = threadIdx.x, wave = tid >> 6, lane = tid & 63;
  const int wm = (wave & 1) * 64, wn = (wave >> 1) * 64;
  const int g = lane >> 4, lr = lane & 15;
  const float scale = 0.03608439182435161f;  // 1/sqrt(768)

  if (wsel == 2) {
    // Two-phase 128x64 LDS transpose; stride 67 spreads banks.
    bf16* tile = smem;
#pragma unroll
    for (int ph = 0; ph < 2; ph++) {
      __syncthreads();
      if ((wave >> 1) == ph) {
#pragma unroll
        for (int i = 0; i < 4; i++)
#pragma unroll
          for (int j = 0; j < 4; j++)
#pragma unroll
            for (int r = 0; r < 4; r++)
              tile[(wm + i * 16 + g * 4 + r) * 67 + j * 16 + lr] =
                  __float2bfloat16(acc[i][j][r]);
      }
      __syncthreads();
      int cl = tid >> 2;          // column within this 64-col half
      int r0 = (tid & 3) * 32;    // row segment (mult of 32)
      bf16 vals[32];
#pragma unroll
      for (int q = 0; q < 32; q++) vals[q] = tile[(r0 + q) * 67 + cl];
      // Vt fragment-tiled: row n (V output col), k = seq (m0+r0+q), K=SEQ.
      int n = n0 + ph * 64 + cl;
      size_t vbase = (size_t)(n >> 4) * 16 * SEQ +
                     ((size_t)((m0 + r0) >> 5) << 9) + (size_t)(n & 15) * 8;
#pragma unroll
      for (int qb = 0; qb < 4; qb++)   // chunk qb -> +qb*16 slots = +qb*128 elems
        *(uint4*)(Vt + vbase + qb * 128) = *(const uint4*)(vals + qb * 8);
    }
  } else {
    bf16* dstm = (wsel == 0) ? Q : Kb;
    float fs = (wsel == 0) ? scale : 1.0f;
#pragma unroll
    for (int i = 0; i < 4; i++)
#pragma unroll
      for (int j = 0; j < 4; j++)
#pragma unroll
        for (int r = 0; r < 4; r++) {
          int row = m0 + wm + i * 16 + g * 4 + r;
          int col = n0 + wn + j * 16 + lr;
          dstm[tiled_off(row, col, DIM)] = __float2bfloat16(acc[i][j][r] * fs);
        }
  }
}

// ---- K2: S = Q K^T; P = exp(S); row sums -> denom.
// 256x256-tile deep-pipelined core: 512 thr, 8 waves (2Mx4N), BK=32,
// 4-deep LDS K-tile queue, counted vmcnt(8), setprio around MFMA.
// Tiled operands: each stage instruction = contiguous 1KB; LDS lane-linear.
// grid (16,16) = 256 blocks = 1/CU; XCD-swizzled.
#define SC_NT (DIM / 32)   // 24 K-tiles

__global__ __launch_bounds__(512, 2) void score_kernel(
    const bf16* __restrict__ Q, const bf16* __restrict__ Kb,
    bf16* __restrict__ P, float* __restrict__ denom) {
  // A queue: 4 x [16 subtiles x 512] at smem+0 ; B queue at smem+32768
  __shared__ __align__(16) bf16 smem[65536];   // 128 KiB
  const int tid  = threadIdx.x;
  const int wave = tid >> 6, lane = tid & 63;
  const int g = lane >> 4, lr = lane & 15;
  const int wm = wave >> 2, wn = wave & 3;     // 2M x 4N wave grid

  const int id  = blockIdx.y * 16 + blockIdx.x;  // 0..255
  const int xcd = id & 7;
  const int k   = id >> 3;                       // 0..31
  const int m0  = (xcd * 2 + (k & 1)) * 256;     // 16 m-tiles
  const int n0  = (k >> 1) * 256;                // 16 n-tiles
  const int rtA = m0 >> 4, rtB = n0 >> 4;

  // STAGE(TT,H): one 16x32 block per operand; contiguous 1KB global read.
#define SC_STAGE(TT, H)                                                        \
  {                                                                            \
    const int rt_ = (H) * 8 + wave;                                            \
    gload_lds16(Q + ((size_t)(rtA + rt_) * 24 + (TT)) * 512 + lane * 8,        \
                smem + ((TT) & 3) * 8192 + rt_ * 512);                         \
    gload_lds16(Kb + ((size_t)(rtB + rt_) * 24 + (TT)) * 512 + lane * 8,       \
                smem + 32768 + ((TT) & 3) * 8192 + rt_ * 512);                 \
  }

  f32x4 acc[8][4] = {};   // 8 m-frags x 4 n-frags

  // prologue: stage K-tiles 0,1,2 (12 loads/lane); tile0 landed after vmcnt(8)
#pragma unroll
  for (int t = 0; t < 3; ++t) {
    SC_STAGE(t, 0);
    SC_STAGE(t, 1);
  }
  asm volatile("s_waitcnt vmcnt(8)" ::: "memory");
  __builtin_amdgcn_s_barrier();

  short8 bfr[4], af[4];
  for (int T = 0; T < SC_NT; ++T) {
    bf16* sA = smem + (T & 3) * 8192;
    bf16* sB = smem + 32768 + (T & 3) * 8192;
    // ---------- phase 0: B all 4 n-frags + A m-frags 0..3 ----------
#pragma unroll
    for (int j = 0; j < 4; ++j)
      bfr[j] = *(const short8*)&sB[(wn * 4 + j) * 512 + lane * 8];
#pragma unroll
    for (int i = 0; i < 4; ++i)
      af[i] = *(const short8*)&sA[(wm * 8 + i) * 512 + lane * 8];
    if (T + 3 < SC_NT) SC_STAGE(T + 3, 0);
    __builtin_amdgcn_s_barrier();
    asm volatile("s_waitcnt lgkmcnt(0)" ::: "memory");
    __builtin_amdgcn_sched_barrier(0);
    __builtin_amdgcn_s_setprio(1);
#pragma unroll
    for (int i = 0; i < 4; ++i)
#pragma unroll
      for (int j = 0; j < 4; ++j)
        acc[i][j] = __builtin_amdgcn_mfma_f32_16x16x32_bf16(af[i], bfr[j], acc[i][j], 0, 0, 0);
    __builtin_amdgcn_s_setprio(0);
    __builtin_amdgcn_s_barrier();
    // ---------- phase 1: A m-frags 4..7 (B reused from regs) ----------
#pragma unroll
    for (int i = 0; i < 4; ++i)
      af[i] = *(const short8*)&sA[(wm * 8 + 4 + i) * 512 + lane * 8];
    if (T + 3 < SC_NT) {
      SC_STAGE(T + 3, 1);
      asm volatile("s_waitcnt vmcnt(8)" ::: "memory");  // tile T+1 landed
    } else {
      asm volatile("s_waitcnt vmcnt(0)" ::: "memory");  // tail drain
    }
    __builtin_amdgcn_s_barrier();
    asm volatile("s_waitcnt lgkmcnt(0)" ::: "memory");
    __builtin_amdgcn_sched_barrier(0);
    __builtin_amdgcn_s_setprio(1);
#pragma unroll
    for (int i = 0; i < 4; ++i)
#pragma unroll
      for (int j = 0; j < 4; ++j)
        acc[4 + i][j] = __builtin_amdgcn_mfma_f32_16x16x32_bf16(af[i], bfr[j], acc[4 + i][j], 0, 0, 0);
    __builtin_amdgcn_s_setprio(0);
    __builtin_amdgcn_s_barrier();
  }
#undef SC_STAGE

  // epilogue: exp, P write (fragment-tiled, K=SEQ), denom atomics.
  const int mrow = m0 + wm * 128;
  const int ncol = n0 + wn * 64;
#pragma unroll
  for (int i = 0; i < 8; ++i) {
    float rsum[4] = {0.f, 0.f, 0.f, 0.f};
#pragma unroll
    for (int j = 0; j < 4; ++j)
#pragma unroll
      for (int r = 0; r < 4; ++r) {
        float p = __expf(acc[i][j][r]);
        int row = mrow + i * 16 + g * 4 + r;
        int col = ncol + j * 16 + lr;
        P[tiled_off(row, col, SEQ)] = __float2bfloat16(p);
        rsum[r] += p;
      }
#pragma unroll
    for (int r = 0; r < 4; ++r) {
      float s = rsum[r];
      s += __shfl_xor(s, 1);
      s += __shfl_xor(s, 2);
      s += __shfl_xor(s, 4);
      s += __shfl_xor(s, 8);
      if (lr == 0) atomicAdd(&denom[mrow + i * 16 + g * 4 + r], s);
    }
  }
}

// ---- K3a: split-K PV. grid (32, 6, 4), XCD-swizzled. bf16 partials
// (row-major, consumed linearly by reduce).
__global__ __launch_bounds__(256, 3) void pv_kernel(
    const bf16* __restrict__ P, const bf16* __restrict__ Vt,
    bf16* __restrict__ partial) {
  __shared__ __align__(16) bf16 smem[16384];
  bf16* lA = smem;
  bf16* lB = smem + 8192;
  // swizzle: XCD gets 3 (z,n) pairs x all 32 m: Vt chunk (256KB) L2-hot
  // across the 32 consecutive same-XCD blocks that reuse it.
  const int id  = (blockIdx.z * 6 + blockIdx.y) * 32 + blockIdx.x;  // 0..767
  const int xcd = id & 7;
  const int k   = id >> 3;          // 0..95
  const int m0  = (k & 31) * 128;
  const int pairid = xcd * 3 + (k >> 5);  // 0..23
  const int zz  = pairid / 6;
  const int n0  = (pairid % 6) * 128;
  f32x4 acc[4][4] = {};
  // K-window: kts [zz*32, zz*32+32) of SEQ/32=128
  gemm_core_t(P, Vt, SEQ / 32, 32, m0, n0, zz * 32, acc, lA, lB);

  bf16* pout = partial + (size_t)zz * SEQ * DIM;
  const int tid = threadIdx.x, wave = tid >> 6, lane = tid & 63;
  const int wm = (wave & 1) * 64, wn = (wave >> 1) * 64;
  const int g = lane >> 4, lr = lane & 15;
#pragma unroll
  for (int i = 0; i < 4; i++)
#pragma unroll
    for (int j = 0; j < 4; j++)
#pragma unroll
      for (int r = 0; r < 4; r++) {
        int row = m0 + wm + i * 16 + g * 4 + r;
        int col = n0 + wn + j * 16 + lr;
        pout[row * DIM + col] = __float2bfloat16(acc[i][j][r]);
      }
}

// ---- K3b: out = (sum_z partial[z]) / denom[row]. 8 elems/thread.
__global__ __launch_bounds__(256) void reduce_kernel(
    const bf16* __restrict__ partial, const float* __restrict__ denom,
    float* __restrict__ out) {
  const size_t stride = (size_t)SEQ * DIM;
  int i = (blockIdx.x * 256 + threadIdx.x) * 8;
  uint4 u0 = *(const uint4*)(partial + i);
  uint4 u1 = *(const uint4*)(partial + stride + i);
  uint4 u2 = *(const uint4*)(partial + 2 * stride + i);
  uint4 u3 = *(const uint4*)(partial + 3 * stride + i);
  bf16 a0[8], a1[8], a2[8], a3[8];
  *(uint4*)a0 = u0; *(uint4*)a1 = u1; *(uint4*)a2 = u2; *(uint4*)a3 = u3;
  float inv = 1.0f / denom[i / DIM];   // 8 | DIM: all 8 elems same row
  float o[8];
#pragma unroll
  for (int k = 0; k < 8; k++)
    o[k] = (__bfloat162float(a0[k]) + __bfloat162float(a1[k]) +
            __bfloat162float(a2[k]) + __bfloat162float(a3[k])) * inv;
  *(float4*)(out + i)     = *(const float4*)(o);
  *(float4*)(out + i + 4) = *(const float4*)(o + 4);
}

extern "C" void kernel_launch(void* const* d_in, const int* in_sizes, int n_in,
                              void* d_out, int out_size, void* d_ws, size_t ws_size,
                              hipStream_t stream) {
  const float* x_raw  = (const float*)d_in[0];
  const float* Wq_raw = (const float*)d_in[1];
  const float* Wk_raw = (const float*)d_in[2];
  const float* Wv_raw = (const float*)d_in[3];
  float* out = (float*)d_out;

  // ws layout (~86 MB): all GEMM operands fragment-tiled (same sizes)
  bf16* xc  = (bf16*)d_ws;
  bf16* Wqc = xc  + (size_t)SEQ * DIM;
  bf16* Wkc = Wqc + (size_t)DIM * DIM;
  bf16* Wvc = Wkc + (size_t)DIM * DIM;
  bf16* Q   = Wvc + (size_t)DIM * DIM;
  bf16* Kb  = Q   + (size_t)SEQ * DIM;
  bf16* Vt  = Kb  + (size_t)SEQ * DIM;
  bf16* P   = Vt  + (size_t)DIM * SEQ;
  float* denom  = (float*)(P + (size_t)SEQ * SEQ);
  bf16* partial = (bf16*)(denom + SEQ);

  const int nx = SEQ * DIM;   // 3,145,728
  const int nw = DIM * DIM;   //   589,824
  const int conv_blocks = nx / 2048 + 3 * (nw / 2048);  // 2400

  convert_all_kernel<<<conv_blocks, 256, 0, stream>>>(
      x_raw, Wq_raw, Wk_raw, Wv_raw, xc, Wqc, Wkc, Wvc, denom);
  qkv_kernel<<<dim3(SEQ / 128, 2304 / 128), 256, 0, stream>>>(xc, Wqc, Wkc, Wvc, Q, Kb, Vt);
  score_kernel<<<dim3(16, 16), 512, 0, stream>>>(Q, Kb, P, denom);
  pv_kernel<<<dim3(SEQ / 128, DIM / 128, 4), 256, 0, stream>>>(P, Vt, partial);
  reduce_kernel<<<nx / 8 / 256, 256, 0, stream>>>(partial, denom, out);
}

// Round 6
// 167.642 us; speedup vs baseline: 1.3092x; 1.0460x over previous
//
#include <hip/hip_runtime.h>
#include <hip/hip_bf16.h>

using bf16 = __hip_bfloat16;
typedef __attribute__((ext_vector_type(4))) float f32x4;
typedef __attribute__((ext_vector_type(8))) short short8;

#define SEQ 4096
#define DIM 768

// r15: all three GEMMs on the m97-class 128^2 core (4 waves, 3 blocks/CU)
// over the r14 fragment-TILED global layout. r12/r14's 256^2 1-block/CU
// pipeline measured 531 TF (=m233's 2-phase stall regime; conflicts=0 did
// not move it -> latency/lockstep-bound, not LDS-bound); reverted. Tiled
// layout keeps: zero bank conflicts (verified r14), contiguous-1KB staging
// (sgpr_base + lane*16B, kills the m80 VALU-bound staging addr calc), 30ms
// outlier gone. r11 166us (conflicted core), r14 175us; pred ~158-163us.

__device__ __forceinline__ size_t tiled_off(int r, int c, int K) {
  // bf16-element offset of (r,c) in a fragment-tiled [R][K] matrix
  return (size_t)(r >> 4) * 16 * K + ((size_t)(c >> 5) << 9) +
         (size_t)((((c >> 3) & 3) << 4) + (r & 15)) * 8 + (c & 7);
}

// ---- fused fp32 -> bf16 canonicalization (RNE) + denom zeroing ----
// writes bf16 in fragment-tiled layout (16B chunks -> one slot each)
__global__ void convert_all_kernel(const float* __restrict__ x,
                                   const float* __restrict__ wq,
                                   const float* __restrict__ wk,
                                   const float* __restrict__ wv,
                                   bf16* __restrict__ xc, bf16* __restrict__ wqc,
                                   bf16* __restrict__ wkc, bf16* __restrict__ wvc,
                                   float* __restrict__ denom) {
  const int XB = (SEQ * DIM) / 2048;   // 1536
  const int WB = (DIM * DIM) / 2048;   // 288
  int b = blockIdx.x;
  if (b == 0) {  // zero denom[4096]
    float4 z = {0.f, 0.f, 0.f, 0.f};
#pragma unroll
    for (int q = 0; q < 4; q++)
      *(float4*)(denom + threadIdx.x * 4 + q * 1024) = z;
  }
  const float* src; bf16* dst; int off;
  if (b < XB)               { src = x;  dst = xc;  off = b * 2048; }
  else if (b < XB + WB)     { src = wq; dst = wqc; off = (b - XB) * 2048; }
  else if (b < XB + 2 * WB) { src = wk; dst = wkc; off = (b - XB - WB) * 2048; }
  else                      { src = wv; dst = wvc; off = (b - XB - 2 * WB) * 2048; }
  int i = off + threadIdx.x * 8;       // flat index; 8 | i
  float4 f0 = *(const float4*)(src + i);
  float4 f1 = *(const float4*)(src + i + 4);
  bf16 tmp[8];
  tmp[0] = __float2bfloat16(f0.x); tmp[1] = __float2bfloat16(f0.y);
  tmp[2] = __float2bfloat16(f0.z); tmp[3] = __float2bfloat16(f0.w);
  tmp[4] = __float2bfloat16(f1.x); tmp[5] = __float2bfloat16(f1.y);
  tmp[6] = __float2bfloat16(f1.z); tmp[7] = __float2bfloat16(f1.w);
  int r = i / DIM, c = i % DIM;        // c multiple of 8
  *(uint4*)(dst + tiled_off(r, c, DIM)) = *(const uint4*)tmp;
}

// ============ shared helpers ============
__device__ __forceinline__ void gload_lds16(const bf16* g, bf16* l) {
  __builtin_amdgcn_global_load_lds(
      (const __attribute__((address_space(1))) void*)g,
      (__attribute__((address_space(3))) void*)l,
      16, 0, 0);
}

// ============ BT-GEMM core on tiled operands (m97-class) ============
// Stage: one instruction = one 16x32 block = contiguous 1KB (lane*16B),
// lands in LDS already in fragment-read order. Reads lane-linear (0-conflict).
__device__ __forceinline__ void gemm_core_t(const bf16* __restrict__ At,
                                            const bf16* __restrict__ Bt,
                                            int Kblk /* K/32 */, int nkt,
                                            int m0, int n0, int kt0,
                                            f32x4 acc[4][4],
                                            bf16* lA, bf16* lB) {
  const int tid  = threadIdx.x;
  const int wave = tid >> 6, lane = tid & 63;
  const int sma = (wave & 1) * 4;   // A subtile base (0 or 4)
  const int smb = (wave >> 1) * 4;  // B subtile base
  const int rtA = m0 >> 4, rtB = n0 >> 4;
  for (int t = 0; t < nkt; t += 2) {
    const int ktb = kt0 + t;
#pragma unroll
    for (int h = 0; h < 2; h++)
#pragma unroll
      for (int s = 0; s < 2; s++) {
        gload_lds16(At + ((size_t)(rtA + wave * 2 + s) * Kblk + ktb + h) * 512 + lane * 8,
                    lA + wave * 1024 + h * 4096 + s * 512);
        gload_lds16(Bt + ((size_t)(rtB + wave * 2 + s) * Kblk + ktb + h) * 512 + lane * 8,
                    lB + wave * 1024 + h * 4096 + s * 512);
      }
    __syncthreads();  // vmcnt drain (DMA done) + barrier
#pragma unroll
    for (int h = 0; h < 2; h++) {
      short8 af[4], bfr[4];
#pragma unroll
      for (int i = 0; i < 4; i++)
        af[i] = *(const short8*)&lA[h * 4096 + (sma + i) * 512 + lane * 8];
#pragma unroll
      for (int j = 0; j < 4; j++)
        bfr[j] = *(const short8*)&lB[h * 4096 + (smb + j) * 512 + lane * 8];
#pragma unroll
      for (int i = 0; i < 4; i++)
#pragma unroll
        for (int j = 0; j < 4; j++)
          acc[i][j] = __builtin_amdgcn_mfma_f32_16x16x32_bf16(af[i], bfr[j], acc[i][j], 0, 0, 0);
    }
    __syncthreads();
  }
}

// C/D layout (verified m89/m91): col = lane&15, row = (lane>>4)*4 + reg.

// ---- K1: fused QKV projection. grid (32, 18), XCD-swizzled. Q gets softmax
// scale folded; Q/Kb written fragment-tiled; V written transposed+tiled.
__global__ __launch_bounds__(256, 3) void qkv_kernel(
    const bf16* __restrict__ x, const bf16* __restrict__ Wq,
    const bf16* __restrict__ Wk, const bf16* __restrict__ Wv,
    bf16* __restrict__ Q, bf16* __restrict__ Kb, bf16* __restrict__ Vt) {
  __shared__ __align__(16) bf16 smem[16384];  // lA|lB for gemm; tile for transpose
  bf16* lA = smem;
  bf16* lB = smem + 8192;
  // swizzle: XCD (id%8) gets m-slab of 4 tiles x all 18 n-tiles (x-slab hot in L2)
  const int id  = blockIdx.y * 32 + blockIdx.x;  // 0..575
  const int xcd = id & 7;
  const int k   = id >> 3;                       // 0..71
  const int m0  = (xcd * 4 + (k & 3)) * 128;
  const int n0g = (k >> 2) * 128;                // 0..17 tiles
  const int wsel = n0g / DIM;          // 0=Q 1=K 2=V (uniform per block)
  const int n0   = n0g % DIM;
  const bf16* W = (wsel == 0) ? Wq : (wsel == 1) ? Wk : Wv;
  f32x4 acc[4][4] = {};
  gemm_core_t(x, W, DIM / 32, DIM / 32, m0, n0, 0, acc, lA, lB);

  const int tid = threadIdx.x, wave = tid >> 6, lane = tid & 63;
  const int wm = (wave & 1) * 64, wn = (wave >> 1) * 64;
  const int g = lane >> 4, lr = lane & 15;
  const float scale = 0.03608439182435161f;  // 1/sqrt(768)

  if (wsel == 2) {
    // Two-phase 128x64 LDS transpose; stride 67 spreads banks.
    bf16* tile = smem;
#pragma unroll
    for (int ph = 0; ph < 2; ph++) {
      __syncthreads();
      if ((wave >> 1) == ph) {
#pragma unroll
        for (int i = 0; i < 4; i++)
#pragma unroll
          for (int j = 0; j < 4; j++)
#pragma unroll
            for (int r = 0; r < 4; r++)
              tile[(wm + i * 16 + g * 4 + r) * 67 + j * 16 + lr] =
                  __float2bfloat16(acc[i][j][r]);
      }
      __syncthreads();
      int cl = tid >> 2;          // column within this 64-col half
      int r0 = (tid & 3) * 32;    // row segment (mult of 32)
      bf16 vals[32];
#pragma unroll
      for (int q = 0; q < 32; q++) vals[q] = tile[(r0 + q) * 67 + cl];
      // Vt fragment-tiled: row n (V output col), k = seq (m0+r0+q), K=SEQ.
      int n = n0 + ph * 64 + cl;
      size_t vbase = (size_t)(n >> 4) * 16 * SEQ +
                     ((size_t)((m0 + r0) >> 5) << 9) + (size_t)(n & 15) * 8;
#pragma unroll
      for (int qb = 0; qb < 4; qb++)   // chunk qb -> +qb*16 slots = +qb*128 elems
        *(uint4*)(Vt + vbase + qb * 128) = *(const uint4*)(vals + qb * 8);
    }
  } else {
    bf16* dstm = (wsel == 0) ? Q : Kb;
    float fs = (wsel == 0) ? scale : 1.0f;
#pragma unroll
    for (int i = 0; i < 4; i++)
#pragma unroll
      for (int j = 0; j < 4; j++)
#pragma unroll
        for (int r = 0; r < 4; r++) {
          int row = m0 + wm + i * 16 + g * 4 + r;
          int col = n0 + wn + j * 16 + lr;
          dstm[tiled_off(row, col, DIM)] = __float2bfloat16(acc[i][j][r] * fs);
        }
  }
}

// ---- K2: S = Q K^T; P = exp(S); row sums -> denom. grid (32,32),
// XCD-swizzled, m97-class 128^2 core on tiled Q/Kb; P written tiled.
__global__ __launch_bounds__(256, 3) void score_kernel(
    const bf16* __restrict__ Q, const bf16* __restrict__ Kb,
    bf16* __restrict__ P, float* __restrict__ denom) {
  __shared__ __align__(16) bf16 smem[16384];
  bf16* lA = smem;
  bf16* lB = smem + 8192;
  // swizzle: XCD (id%8) gets m-slab of 4 Q-tiles (L2-hot) x all 32 n.
  const int id  = blockIdx.y * 32 + blockIdx.x;  // 0..1023
  const int xcd = id & 7;
  const int k   = id >> 3;                       // 0..127
  const int m0  = (xcd * 4 + (k & 3)) * 128;
  const int n0  = (k >> 2) * 128;
  f32x4 acc[4][4] = {};
  gemm_core_t(Q, Kb, DIM / 32, DIM / 32, m0, n0, 0, acc, lA, lB);

  const int tid = threadIdx.x, wave = tid >> 6, lane = tid & 63;
  const int wm = (wave & 1) * 64, wn = (wave >> 1) * 64;
  const int g = lane >> 4, lr = lane & 15;
#pragma unroll
  for (int i = 0; i < 4; i++) {
    float rsum[4] = {0.f, 0.f, 0.f, 0.f};
#pragma unroll
    for (int j = 0; j < 4; j++)
#pragma unroll
      for (int r = 0; r < 4; r++) {
        float p = __expf(acc[i][j][r]);
        int row = m0 + wm + i * 16 + g * 4 + r;
        int col = n0 + wn + j * 16 + lr;
        P[tiled_off(row, col, SEQ)] = __float2bfloat16(p);
        rsum[r] += p;
      }
#pragma unroll
    for (int r = 0; r < 4; r++) {
      float s = rsum[r];
      s += __shfl_xor(s, 1);
      s += __shfl_xor(s, 2);
      s += __shfl_xor(s, 4);
      s += __shfl_xor(s, 8);
      if (lr == 0) atomicAdd(&denom[m0 + wm + i * 16 + g * 4 + r], s);
    }
  }
}

// ---- K3a: split-K PV. grid (32, 6, 4), XCD-swizzled. bf16 partials
// (row-major, consumed linearly by reduce).
__global__ __launch_bounds__(256, 3) void pv_kernel(
    const bf16* __restrict__ P, const bf16* __restrict__ Vt,
    bf16* __restrict__ partial) {
  __shared__ __align__(16) bf16 smem[16384];
  bf16* lA = smem;
  bf16* lB = smem + 8192;
  // swizzle: XCD gets 3 (z,n) pairs x all 32 m: Vt chunk L2-hot
  // across the 32 consecutive same-XCD blocks that reuse it.
  const int id  = (blockIdx.z * 6 + blockIdx.y) * 32 + blockIdx.x;  // 0..767
  const int xcd = id & 7;
  const int k   = id >> 3;          // 0..95
  const int m0  = (k & 31) * 128;
  const int pairid = xcd * 3 + (k >> 5);  // 0..23
  const int zz  = pairid / 6;
  const int n0  = (pairid % 6) * 128;
  f32x4 acc[4][4] = {};
  // K-window: kts [zz*32, zz*32+32) of SEQ/32=128
  gemm_core_t(P, Vt, SEQ / 32, 32, m0, n0, zz * 32, acc, lA, lB);

  bf16* pout = partial + (size_t)zz * SEQ * DIM;
  const int tid = threadIdx.x, wave = tid >> 6, lane = tid & 63;
  const int wm = (wave & 1) * 64, wn = (wave >> 1) * 64;
  const int g = lane >> 4, lr = lane & 15;
#pragma unroll
  for (int i = 0; i < 4; i++)
#pragma unroll
    for (int j = 0; j < 4; j++)
#pragma unroll
      for (int r = 0; r < 4; r++) {
        int row = m0 + wm + i * 16 + g * 4 + r;
        int col = n0 + wn + j * 16 + lr;
        pout[row * DIM + col] = __float2bfloat16(acc[i][j][r]);
      }
}

// ---- K3b: out = (sum_z partial[z]) / denom[row]. 8 elems/thread.
__global__ __launch_bounds__(256) void reduce_kernel(
    const bf16* __restrict__ partial, const float* __restrict__ denom,
    float* __restrict__ out) {
  const size_t stride = (size_t)SEQ * DIM;
  int i = (blockIdx.x * 256 + threadIdx.x) * 8;
  uint4 u0 = *(const uint4*)(partial + i);
  uint4 u1 = *(const uint4*)(partial + stride + i);
  uint4 u2 = *(const uint4*)(partial + 2 * stride + i);
  uint4 u3 = *(const uint4*)(partial + 3 * stride + i);
  bf16 a0[8], a1[8], a2[8], a3[8];
  *(uint4*)a0 = u0; *(uint4*)a1 = u1; *(uint4*)a2 = u2; *(uint4*)a3 = u3;
  float inv = 1.0f / denom[i / DIM];   // 8 | DIM: all 8 elems same row
  float o[8];
#pragma unroll
  for (int k = 0; k < 8; k++)
    o[k] = (__bfloat162float(a0[k]) + __bfloat162float(a1[k]) +
            __bfloat162float(a2[k]) + __bfloat162float(a3[k])) * inv;
  *(float4*)(out + i)     = *(const float4*)(o);
  *(float4*)(out + i + 4) = *(const float4*)(o + 4);
}

extern "C" void kernel_launch(void* const* d_in, const int* in_sizes, int n_in,
                              void* d_out, int out_size, void* d_ws, size_t ws_size,
                              hipStream_t stream) {
  const float* x_raw  = (const float*)d_in[0];
  const float* Wq_raw = (const float*)d_in[1];
  const float* Wk_raw = (const float*)d_in[2];
  const float* Wv_raw = (const float*)d_in[3];
  float* out = (float*)d_out;

  // ws layout (~86 MB): all GEMM operands fragment-tiled (same sizes)
  bf16* xc  = (bf16*)d_ws;
  bf16* Wqc = xc  + (size_t)SEQ * DIM;
  bf16* Wkc = Wqc + (size_t)DIM * DIM;
  bf16* Wvc = Wkc + (size_t)DIM * DIM;
  bf16* Q   = Wvc + (size_t)DIM * DIM;
  bf16* Kb  = Q   + (size_t)SEQ * DIM;
  bf16* Vt  = Kb  + (size_t)SEQ * DIM;
  bf16* P   = Vt  + (size_t)DIM * SEQ;
  float* denom  = (float*)(P + (size_t)SEQ * SEQ);
  bf16* partial = (bf16*)(denom + SEQ);

  const int nx = SEQ * DIM;   // 3,145,728
  const int nw = DIM * DIM;   //   589,824
  const int conv_blocks = nx / 2048 + 3 * (nw / 2048);  // 2400

  convert_all_kernel<<<conv_blocks, 256, 0, stream>>>(
      x_raw, Wq_raw, Wk_raw, Wv_raw, xc, Wqc, Wkc, Wvc, denom);
  qkv_kernel<<<dim3(SEQ / 128, 2304 / 128), 256, 0, stream>>>(xc, Wqc, Wkc, Wvc, Q, Kb, Vt);
  score_kernel<<<dim3(SEQ / 128, SEQ / 128), 256, 0, stream>>>(Q, Kb, P, denom);
  pv_kernel<<<dim3(SEQ / 128, DIM / 128, 4), 256, 0, stream>>>(P, Vt, partial);
  reduce_kernel<<<nx / 8 / 256, 256, 0, stream>>>(partial, denom, out);
}